// Round 17
// baseline (88.774 us; speedup 1.0000x reference)
//
#include <hip/hip_runtime.h>

#define BB 4
#define NN 512
#define MM 4096
#define DD 256
#define HH 8
#define HDD 32

typedef __attribute__((ext_vector_type(8))) short bf16x8;
typedef __attribute__((ext_vector_type(4))) float f32x4;
typedef __attribute__((ext_vector_type(4))) unsigned int u32x4;

__device__ __forceinline__ unsigned short f2b(float f) {
    union { float f; unsigned u; } v; v.f = f;
    unsigned r = v.u + 0x7fffu + ((v.u >> 16) & 1u);
    return (unsigned short)(r >> 16);
}
__device__ __forceinline__ float b2f(unsigned short u) {
    union { unsigned u; float f; } v; v.u = ((unsigned)u) << 16;
    return v.f;
}
// packed f32x2 -> bf16x2 (RNE)
__device__ __forceinline__ unsigned cvt_pk_bf16(float lo, float hi) {
    unsigned r;
    asm("v_cvt_pk_bf16_f32 %0, %1, %2" : "=v"(r) : "v"(lo), "v"(hi));
    return r;
}

// ---------------------------------------------------------------------------
// Weight convert+transpose via LDS tile. Wt[c][k] = bf16(W[k][c]).
// ---------------------------------------------------------------------------
struct WPack { const float* s[6]; unsigned short* d[6]; };
__global__ __launch_bounds__(256) void convert_w(WPack p)
{
    __shared__ unsigned short T[64][72];
    const int mat = blockIdx.x >> 4;
    const int tile = blockIdx.x & 15;
    const int kt = (tile >> 2) * 64, ct = (tile & 3) * 64;
    const int t = threadIdx.x;
    const int kl = t >> 2, cseg = (t & 3) * 16;

    const float* src = &p.s[mat][(size_t)(kt + kl) * DD + ct + cseg];
    #pragma unroll
    for (int j4 = 0; j4 < 4; ++j4) {
        const float4 f = *(const float4*)(src + j4 * 4);
        T[cseg + j4 * 4 + 0][kl] = f2b(f.x);
        T[cseg + j4 * 4 + 1][kl] = f2b(f.y);
        T[cseg + j4 * 4 + 2][kl] = f2b(f.z);
        T[cseg + j4 * 4 + 3][kl] = f2b(f.w);
    }
    __syncthreads();
    unsigned short* dst = &p.d[mat][(size_t)(ct + kl) * DD + kt + cseg];
    *(bf16x8*)dst       = *(const bf16x8*)&T[kl][cseg];
    *(bf16x8*)(dst + 8) = *(const bf16x8*)&T[kl][cseg + 8];
}

// ---------------------------------------------------------------------------
// Fused input projections: one block stages the f32 A tile ONCE per K-step
// and computes BOTH the qk-projection (head-packed out, scaled) and the
// V-projection (permuted-VT out, optional row mask) for that row-panel.
// (last-green version, 256 threads, grid (289,4))
// ---------------------------------------------------------------------------
struct InPack {
    const float* amr; const float* vis;
    const unsigned short *Wqa, *Wva, *Wqv, *Wvv;
    unsigned short *amr_qk, *vis_qk, *VTa, *VTv;
    const int* mask;
    unsigned short* keepP;   // bf16 keep flags, VT-permuted, [B][NN]
    float sqs;
};
__global__ __launch_bounds__(256) void gemm_in(InPack p)
{
    __shared__ unsigned short As[64][72];
    __shared__ unsigned short Wq[64][72];
    __shared__ unsigned short Wv[64][72];

    const int bx = blockIdx.x;
    if (bx == 288) {
        if (blockIdx.y == 0) {
            // build keepP: bf16(mask?0:1) stored in the VT-permuted m order
            #pragma unroll
            for (int k8 = 0; k8 < 8; ++k8) {
                const int idx = k8 * 256 + threadIdx.x;
                const int m = idx & (NN - 1);
                const int r = m & 31;
                const int pp = ((r & 15) >> 2) * 8 + (r >> 4) * 4 + (r & 3);
                p.keepP[(idx & ~(NN - 1)) | (m & ~31) | pp]
                    = p.mask[idx] ? (unsigned short)0 : (unsigned short)0x3F80;
            }
        }
        return;
    }

    const float* A; const unsigned short *Wqm, *Wvm;
    unsigned short *Cq, *VT; const int* rowmask; int SEQ, r0;
    if (bx < 32) {
        A = p.amr; Wqm = p.Wqa; Wvm = p.Wva; Cq = p.amr_qk; VT = p.VTa;
        rowmask = p.mask; SEQ = NN; r0 = bx * 64;
    } else {
        A = p.vis; Wqm = p.Wqv; Wvm = p.Wvv; Cq = p.vis_qk; VT = p.VTv;
        rowmask = nullptr; SEQ = MM; r0 = (bx - 32) * 64;
    }
    const int c0 = blockIdx.y * 64;

    const int tid = threadIdx.x;
    const int lane = tid & 63, w = tid >> 6;
    const int rq = (w >> 1) * 32, cq = (w & 1) * 32;
    const int srow = tid >> 2, skc = (tid & 3) * 16;
    const int g = lane >> 4, cl = lane & 15;

    f32x4 aq[2][2] = {};   // qk-projection acc
    f32x4 av[2][2] = {};   // v-projection acc

    for (int ks = 0; ks < DD; ks += 64) {
        __syncthreads();
        {
            const float* ga = &A[(size_t)(r0 + srow) * DD + ks + skc];
            const float4 f0 = *(const float4*)(ga);
            const float4 f1 = *(const float4*)(ga + 4);
            const float4 f2 = *(const float4*)(ga + 8);
            const float4 f3 = *(const float4*)(ga + 12);
            uint4 u0, u1;
            u0.x = cvt_pk_bf16(f0.x, f0.y); u0.y = cvt_pk_bf16(f0.z, f0.w);
            u0.z = cvt_pk_bf16(f1.x, f1.y); u0.w = cvt_pk_bf16(f1.z, f1.w);
            u1.x = cvt_pk_bf16(f2.x, f2.y); u1.y = cvt_pk_bf16(f2.z, f2.w);
            u1.z = cvt_pk_bf16(f3.x, f3.y); u1.w = cvt_pk_bf16(f3.z, f3.w);
            *(uint4*)&As[srow][skc]     = u0;
            *(uint4*)&As[srow][skc + 8] = u1;
            const unsigned short* gq = &Wqm[(size_t)(c0 + srow) * DD + ks + skc];
            *(bf16x8*)&Wq[srow][skc]     = *(const bf16x8*)gq;
            *(bf16x8*)&Wq[srow][skc + 8] = *(const bf16x8*)(gq + 8);
            const unsigned short* gv = &Wvm[(size_t)(c0 + srow) * DD + ks + skc];
            *(bf16x8*)&Wv[srow][skc]     = *(const bf16x8*)gv;
            *(bf16x8*)&Wv[srow][skc + 8] = *(const bf16x8*)(gv + 8);
        }
        __syncthreads();
        #pragma unroll
        for (int kh = 0; kh < 2; ++kh) {
            const int kk = kh * 32 + g * 8;
            const bf16x8 a0 = *(const bf16x8*)&As[rq + cl][kk];
            const bf16x8 a1 = *(const bf16x8*)&As[rq + 16 + cl][kk];
            const bf16x8 q0 = *(const bf16x8*)&Wq[cq + cl][kk];
            const bf16x8 q1 = *(const bf16x8*)&Wq[cq + 16 + cl][kk];
            const bf16x8 v0 = *(const bf16x8*)&Wv[cq + cl][kk];
            const bf16x8 v1 = *(const bf16x8*)&Wv[cq + 16 + cl][kk];
            aq[0][0] = __builtin_amdgcn_mfma_f32_16x16x32_bf16(a0, q0, aq[0][0], 0, 0, 0);
            aq[0][1] = __builtin_amdgcn_mfma_f32_16x16x32_bf16(a0, q1, aq[0][1], 0, 0, 0);
            aq[1][0] = __builtin_amdgcn_mfma_f32_16x16x32_bf16(a1, q0, aq[1][0], 0, 0, 0);
            aq[1][1] = __builtin_amdgcn_mfma_f32_16x16x32_bf16(a1, q1, aq[1][1], 0, 0, 0);
            av[0][0] = __builtin_amdgcn_mfma_f32_16x16x32_bf16(a0, v0, av[0][0], 0, 0, 0);
            av[0][1] = __builtin_amdgcn_mfma_f32_16x16x32_bf16(a0, v1, av[0][1], 0, 0, 0);
            av[1][0] = __builtin_amdgcn_mfma_f32_16x16x32_bf16(a1, v0, av[1][0], 0, 0, 0);
            av[1][1] = __builtin_amdgcn_mfma_f32_16x16x32_bf16(a1, v1, av[1][1], 0, 0, 0);
        }
    }

    const int b0 = r0 / SEQ, mbase = r0 % SEQ;

    // qk output: head-packed
    #pragma unroll
    for (int sr = 0; sr < 2; ++sr)
    #pragma unroll
    for (int sc = 0; sc < 2; ++sc) {
        const int col = c0 + cq + sc * 16 + cl;
        const int head = col >> 5, c32 = col & 31;
        #pragma unroll
        for (int reg = 0; reg < 4; ++reg) {
            const int m = mbase + rq + sr * 16 + g * 4 + reg;
            Cq[(((size_t)b0 * HH + head) * SEQ + m) * 32 + c32]
                = f2b(aq[sr][sc][reg] * p.sqs);
        }
    }

    // v output: mask rows (dir-B), retile to permuted-VT via LDS
    if (rowmask != nullptr) {
        #pragma unroll
        for (int sr = 0; sr < 2; ++sr)
            #pragma unroll
            for (int reg = 0; reg < 4; ++reg) {
                const int m = mbase + rq + sr * 16 + g * 4 + reg;
                const float k = rowmask[b0 * SEQ + m] ? 0.f : 1.f;
                av[sr][0][reg] *= k;
                av[sr][1][reg] *= k;
            }
    }
    __syncthreads();
    #pragma unroll
    for (int sr = 0; sr < 2; ++sr)
    #pragma unroll
    for (int sc = 0; sc < 2; ++sc) {
        const int col_local = cq + sc * 16 + cl;
        uint2 u;
        u.x = cvt_pk_bf16(av[sr][sc][0], av[sr][sc][1]);
        u.y = cvt_pk_bf16(av[sr][sc][2], av[sr][sc][3]);
        *(uint2*)&As[col_local][rq + g * 8 + sr * 4] = u;
    }
    __syncthreads();
    {
        const int col = tid >> 2, seg = tid & 3;
        unsigned short* dst = &VT[((size_t)b0 * DD + c0 + col) * SEQ + mbase + seg * 16];
        *(bf16x8*)dst       = *(const bf16x8*)&As[col][seg * 16];
        *(bf16x8*)(dst + 8) = *(const bf16x8*)&As[col][seg * 16 + 8];
    }
}

// ---------------------------------------------------------------------------
// Output projection tile (A bf16 ctx row-major): out = (ctx@W + bias)*feats.
// ---------------------------------------------------------------------------
__device__ __forceinline__ void gemm_tile_out(
    const unsigned short* __restrict__ A,
    const unsigned short* __restrict__ Wt,
    const float* __restrict__ bias,
    const float* __restrict__ feats,
    float* __restrict__ Cf,
    int r0, int c0,
    unsigned short (*As)[72], unsigned short (*Ws)[72])
{
    const int tid = threadIdx.x;
    const int lane = tid & 63, w = tid >> 6;
    const int rq = (w >> 1) * 32, cq = (w & 1) * 32;
    const int srow = tid >> 2, skc = (tid & 3) * 16;
    const int g = lane >> 4, cl = lane & 15;

    f32x4 acc[2][2] = {};

    for (int ks = 0; ks < DD; ks += 64) {
        __syncthreads();
        {
            const unsigned short* ga = &A[(size_t)(r0 + srow) * DD + ks + skc];
            *(bf16x8*)&As[srow][skc]     = *(const bf16x8*)ga;
            *(bf16x8*)&As[srow][skc + 8] = *(const bf16x8*)(ga + 8);
            const unsigned short* gw = &Wt[(size_t)(c0 + srow) * DD + ks + skc];
            *(bf16x8*)&Ws[srow][skc]     = *(const bf16x8*)gw;
            *(bf16x8*)&Ws[srow][skc + 8] = *(const bf16x8*)(gw + 8);
        }
        __syncthreads();
        #pragma unroll
        for (int kh = 0; kh < 2; ++kh) {
            const int kk = kh * 32 + g * 8;
            const bf16x8 a0 = *(const bf16x8*)&As[rq + cl][kk];
            const bf16x8 a1 = *(const bf16x8*)&As[rq + 16 + cl][kk];
            const bf16x8 b0 = *(const bf16x8*)&Ws[cq + cl][kk];
            const bf16x8 b1 = *(const bf16x8*)&Ws[cq + 16 + cl][kk];
            acc[0][0] = __builtin_amdgcn_mfma_f32_16x16x32_bf16(a0, b0, acc[0][0], 0, 0, 0);
            acc[0][1] = __builtin_amdgcn_mfma_f32_16x16x32_bf16(a0, b1, acc[0][1], 0, 0, 0);
            acc[1][0] = __builtin_amdgcn_mfma_f32_16x16x32_bf16(a1, b0, acc[1][0], 0, 0, 0);
            acc[1][1] = __builtin_amdgcn_mfma_f32_16x16x32_bf16(a1, b1, acc[1][1], 0, 0, 0);
        }
    }

    #pragma unroll
    for (int sr = 0; sr < 2; ++sr)
    #pragma unroll
    for (int sc = 0; sc < 2; ++sc) {
        const int col = c0 + cq + sc * 16 + cl;
        #pragma unroll
        for (int reg = 0; reg < 4; ++reg) {
            const int row = r0 + rq + sr * 16 + g * 4 + reg;
            const size_t idx = (size_t)row * DD + col;
            Cf[idx] = (acc[sr][sc][reg] + bias[col]) * feats[idx];
        }
    }
}

struct OutPack {
    const unsigned short* A[2];
    const unsigned short* Wt[2];
    const float* bias[2];
    const float* feats[2];
    float* O[2];
};
__global__ __launch_bounds__(256) void gemm_out(OutPack p)
{
    __shared__ unsigned short As[64][72];
    __shared__ unsigned short Ws[64][72];
    const int bx = blockIdx.x;
    const int which = (bx < 32) ? 0 : 1;
    const int rb = (bx < 32) ? bx : bx - 32;
    gemm_tile_out(p.A[which], p.Wt[which], p.bias[which], p.feats[which],
                  p.O[which], rb * 64, blockIdx.y * 64, As, Ws);
}

// ---------------------------------------------------------------------------
// Attention body v10b: last-green v10 + V/keepP fragments prefetched ONE TILE
// AHEAD (pure scheduling; V previously issued only ~150cy before its PV use,
// under L2 latency ~200-400cy). Math and load set identical to last-green.
// ---------------------------------------------------------------------------
template<int SEQK, int SPLIT, bool HAS_KEEP>
__device__ __forceinline__ void attn_body(
    int bid,
    const unsigned short* __restrict__ Qb,    // head-packed [b][h][seq][32]
    const unsigned short* __restrict__ Kb,    // head-packed
    const unsigned short* __restrict__ VTb,   // permuted VT
    const unsigned short* __restrict__ keepP, // bf16 keep flags (permuted) or null
    unsigned short* __restrict__ ctx,         // row-major [b][nq][256]
    float* __restrict__ Pl, unsigned short* __restrict__ PaccB,
    int NQ)
{
    constexpr int KCHUNK = SEQK / SPLIT;
    constexpr int NT = KCHUNK / 64;

    const int lane = threadIdx.x & 63;
    const int g = lane >> 4, cl = lane & 15;

    const int nqt = NQ / 64;
    int bi = bid;
    const int sp = bi % SPLIT; bi /= SPLIT;
    const int qt = bi % nqt;   bi /= nqt;
    const int h  = bi % HH;
    const int b  = bi / HH;
    const int q0 = qt * 64;
    const int kv0 = sp * KCHUNK;

    bf16x8 aq[4];
    #pragma unroll
    for (int qg = 0; qg < 4; ++qg)
        aq[qg] = *(const bf16x8*)
            &Qb[(((size_t)b * HH + h) * NQ + q0 + qg * 16 + cl) * 32 + g * 8];

    const unsigned short* Kp0 = Kb + (((size_t)b * HH + h) * SEQK + kv0 + cl) * 32 + g * 8;
    const unsigned short* Vp0 = VTb + ((size_t)b * DD + h * HDD + cl) * SEQK + kv0 + g * 8;
    const unsigned short* Op0 = HAS_KEEP ? (keepP + (size_t)b * SEQK + kv0 + g * 8) : nullptr;

    union { u32x4 u; bf16x8 b; } onesc;
    onesc.u[0] = 0x3F803F80u; onesc.u[1] = 0x3F803F80u;
    onesc.u[2] = 0x3F803F80u; onesc.u[3] = 0x3F803F80u;

    f32x4 acc[4][2] = {};
    f32x4 acc_l[4] = {};

    bf16x8 Kc[4], Kn[4];
    bf16x8 Vc[2][2], Vn[2][2];
    bf16x8 Oc[2], On[2];

    #pragma unroll
    for (int kf = 0; kf < 4; ++kf)
        Kc[kf] = *(const bf16x8*)(Kp0 + (size_t)(kf * 16) * 32);
    #pragma unroll
    for (int mh = 0; mh < 2; ++mh)
        #pragma unroll
        for (int sub = 0; sub < 2; ++sub)
            Vc[mh][sub] = *(const bf16x8*)(Vp0 + (size_t)(sub * 16) * SEQK + mh * 32);
    if (HAS_KEEP) {
        Oc[0] = *(const bf16x8*)(Op0);
        Oc[1] = *(const bf16x8*)(Op0 + 32);
    } else {
        Oc[0] = onesc.b;
        Oc[1] = onesc.b;
    }

    for (int t = 0; t < NT; ++t) {
        // prefetch tile t+1 (K, V, keep) — a full tile of compute ahead
        if (t + 1 < NT) {
            const unsigned short* kp = Kp0 + (size_t)((t + 1) * 64) * 32;
            #pragma unroll
            for (int kf = 0; kf < 4; ++kf)
                Kn[kf] = *(const bf16x8*)(kp + (size_t)(kf * 16) * 32);
            #pragma unroll
            for (int mh = 0; mh < 2; ++mh)
                #pragma unroll
                for (int sub = 0; sub < 2; ++sub)
                    Vn[mh][sub] = *(const bf16x8*)
                        (Vp0 + (size_t)(sub * 16) * SEQK + (t + 1) * 64 + mh * 32);
            if (HAS_KEEP) {
                On[0] = *(const bf16x8*)(Op0 + (t + 1) * 64);
                On[1] = *(const bf16x8*)(Op0 + (t + 1) * 64 + 32);
            }
        }

        // per-kh: QK (8 MFMA) -> exp+pack -> PV + denom (12 MFMA); mh == kh
        #pragma unroll
        for (int kh = 0; kh < 2; ++kh) {
            f32x4 s[4][2];
            #pragma unroll
            for (int k2 = 0; k2 < 2; ++k2) {
                const f32x4 z = {0.f, 0.f, 0.f, 0.f};
                const bf16x8 kfrag = Kc[kh * 2 + k2];
                #pragma unroll
                for (int qg = 0; qg < 4; ++qg)
                    s[qg][k2] = __builtin_amdgcn_mfma_f32_16x16x32_bf16(
                        kfrag, aq[qg], z, 0, 0, 0);
            }
            union { u32x4 u; bf16x8 b; } pa[4];
            #pragma unroll
            for (int qg = 0; qg < 4; ++qg) {
                pa[qg].u[0] = cvt_pk_bf16(exp2f(s[qg][0][0]), exp2f(s[qg][0][1]));
                pa[qg].u[1] = cvt_pk_bf16(exp2f(s[qg][0][2]), exp2f(s[qg][0][3]));
                pa[qg].u[2] = cvt_pk_bf16(exp2f(s[qg][1][0]), exp2f(s[qg][1][1]));
                pa[qg].u[3] = cvt_pk_bf16(exp2f(s[qg][1][2]), exp2f(s[qg][1][3]));
            }
            #pragma unroll
            for (int sub = 0; sub < 2; ++sub)
                #pragma unroll
                for (int qg = 0; qg < 4; ++qg)
                    acc[qg][sub] = __builtin_amdgcn_mfma_f32_16x16x32_bf16(
                        pa[qg].b, Vc[kh][sub], acc[qg][sub], 0, 0, 0);
            #pragma unroll
            for (int qg = 0; qg < 4; ++qg)
                acc_l[qg] = __builtin_amdgcn_mfma_f32_16x16x32_bf16(
                    pa[qg].b, Oc[kh], acc_l[qg], 0, 0, 0);
        }

        #pragma unroll
        for (int kf = 0; kf < 4; ++kf) Kc[kf] = Kn[kf];
        #pragma unroll
        for (int mh = 0; mh < 2; ++mh)
            #pragma unroll
            for (int sub = 0; sub < 2; ++sub)
                Vc[mh][sub] = Vn[mh][sub];
        if (HAS_KEEP) {
            Oc[0] = On[0];
            Oc[1] = On[1];
        }
    }

    if (SPLIT > 1) {
        const int pb = bid;
        #pragma unroll
        for (int qg = 0; qg < 4; ++qg) {
            #pragma unroll
            for (int sub = 0; sub < 2; ++sub)
                #pragma unroll
                for (int reg = 0; reg < 4; ++reg) {
                    const int wq = qg * 16 + g * 4 + reg;
                    PaccB[((size_t)pb * 64 + wq) * 32 + sub * 16 + cl]
                        = f2b(acc[qg][sub][reg]);
                }
            if (cl == 0) {
                #pragma unroll
                for (int reg = 0; reg < 4; ++reg)
                    Pl[(size_t)pb * 64 + qg * 16 + g * 4 + reg] = acc_l[qg][reg];
            }
        }
    } else {
        // acc_l rows align with acc rows -> direct divide, no shuffles
        #pragma unroll
        for (int qg = 0; qg < 4; ++qg)
            #pragma unroll
            for (int sub = 0; sub < 2; ++sub)
                #pragma unroll
                for (int reg = 0; reg < 4; ++reg) {
                    const int q = q0 + qg * 16 + g * 4 + reg;
                    ctx[((size_t)b * NQ + q) * DD + h * HDD + sub * 16 + cl]
                        = f2b(acc[qg][sub][reg] / acc_l[qg][reg]);
                }
    }
}

// Fused, 1-wave blocks, parity-interleaved: even = dir A (2048, SPLIT=8),
// odd = dir B (2048, keep-masked). Uniform NT=8.
__global__ __launch_bounds__(64) void attn_fused(
    const unsigned short* __restrict__ amr_qk,
    const unsigned short* __restrict__ vis_qk,
    const unsigned short* __restrict__ VT_vis,
    const unsigned short* __restrict__ VT_amr,
    const unsigned short* __restrict__ keepP,
    unsigned short* __restrict__ ctx1,
    float* __restrict__ Pl, unsigned short* __restrict__ PaccB)
{
    if ((blockIdx.x & 1) == 0) {
        attn_body<MM, 8, false>(blockIdx.x >> 1, amr_qk, vis_qk, VT_vis, nullptr,
                                nullptr, Pl, PaccB, NN);
    } else {
        attn_body<NN, 1, true>(blockIdx.x >> 1, vis_qk, amr_qk, VT_amr, keepP,
                               ctx1, nullptr, nullptr, MM);
    }
}

// Combine 8 split partials (bf16 acc, f32 l): out = sum(acc)/sum(l)
// grid = 256 blocks (one per (b,h,qt64)), 256 threads.
__global__ __launch_bounds__(256) void combine_split(
    const float* __restrict__ Pl, const unsigned short* __restrict__ PaccB,
    unsigned short* __restrict__ ctx)
{
    const int t = threadIdx.x;
    const int q = t >> 2, cseg = (t & 3) * 8;
    const int bqt = blockIdx.x;
    const int qt = bqt & 7, h = (bqt >> 3) & 7, b = bqt >> 6;
    const int pb0 = bqt * 8;

    float denom = 0.f;
    float o[8] = {};
    #pragma unroll
    for (int sp = 0; sp < 8; ++sp) {
        const size_t base = ((size_t)(pb0 + sp) * 64 + q) * 32 + cseg;
        const bf16x8 a = *(const bf16x8*)&PaccB[base];
        #pragma unroll
        for (int j = 0; j < 8; ++j)
            o[j] += b2f((unsigned short)a[j]);
        denom += Pl[(size_t)(pb0 + sp) * 64 + q];
    }
    const float inv = 1.f / denom;

    unsigned short* dst = &ctx[((size_t)b * NN + qt * 64 + q) * DD + h * HDD + cseg];
    ushort4 u0, u1;
    u0.x = f2b(o[0] * inv); u0.y = f2b(o[1] * inv);
    u0.z = f2b(o[2] * inv); u0.w = f2b(o[3] * inv);
    u1.x = f2b(o[4] * inv); u1.y = f2b(o[5] * inv);
    u1.z = f2b(o[6] * inv); u1.w = f2b(o[7] * inv);
    *(ushort4*)dst       = u0;
    *(ushort4*)(dst + 4) = u1;
}

// ---------------------------------------------------------------------------
extern "C" void kernel_launch(void* const* d_in, const int* in_sizes, int n_in,
                              void* d_out, int out_size, void* d_ws, size_t ws_size,
                              hipStream_t stream)
{
    const float* amr_feats    = (const float*)d_in[0];
    const int*   amr_pad_mask = (const int*)d_in[1];
    const float* visual_feats = (const float*)d_in[2];
    const float* W_amr_qk     = (const float*)d_in[3];
    const float* W_amr_v      = (const float*)d_in[4];
    const float* W_vis_qk     = (const float*)d_in[5];
    const float* W_vis_v      = (const float*)d_in[6];
    const float* W_amr_out    = (const float*)d_in[7];
    const float* b_amr_out    = (const float*)d_in[8];
    const float* W_vis_out    = (const float*)d_in[9];
    const float* b_vis_out    = (const float*)d_in[10];

    // workspace layout (u16 offsets), total ~38.6 MB
    unsigned short* ws = (unsigned short*)d_ws;
    unsigned short* Wt_amr_qk  = ws;                    // 6 x 65536
    unsigned short* Wt_amr_v   = ws + 65536;
    unsigned short* Wt_vis_qk  = ws + 131072;
    unsigned short* Wt_vis_v   = ws + 196608;
    unsigned short* Wt_amr_out = ws + 262144;
    unsigned short* Wt_vis_out = ws + 327680;
    unsigned short* amr_qk_b   = ws + 393216;           // 524288 (head-packed)
    unsigned short* VT_amr     = ws + 917504;           // 524288 (perm, masked rows zeroed)
    unsigned short* vis_qk_b   = ws + 1441792;          // 4194304 (head-packed)
    unsigned short* VT_vis     = ws + 5636096;          // 4194304
    unsigned short* ctx0_b     = ws + 9830400;          // 524288
    unsigned short* ctx1_b     = ws + 10354688;         // 4194304
    float* Pl                  = (float*)(ws + 14548992);  // 2048*64 f32
    unsigned short* PaccB      = ws + 15073280;         // 2048*64*32 bf16
    unsigned short* keepP      = ws + 19267584;         // 2048 bf16 (permuted)

    float* out0 = (float*)d_out;
    float* out1 = out0 + (size_t)BB * NN * DD;

    // sqrt( HD^-0.5 * log2(e) ) folded into BOTH qk projections -> exp2 domain
    const float SQS = 0.50500976f;

    // 0) weight convert+transpose
    WPack wp;
    wp.s[0] = W_amr_qk;  wp.d[0] = Wt_amr_qk;
    wp.s[1] = W_amr_v;   wp.d[1] = Wt_amr_v;
    wp.s[2] = W_vis_qk;  wp.d[2] = Wt_vis_qk;
    wp.s[3] = W_vis_v;   wp.d[3] = Wt_vis_v;
    wp.s[4] = W_amr_out; wp.d[4] = Wt_amr_out;
    wp.s[5] = W_vis_out; wp.d[5] = Wt_vis_out;
    convert_w<<<96, 256, 0, stream>>>(wp);

    // 1) fused input projections (+ keepP builder block)
    InPack ip;
    ip.amr = amr_feats; ip.vis = visual_feats;
    ip.Wqa = Wt_amr_qk; ip.Wva = Wt_amr_v;
    ip.Wqv = Wt_vis_qk; ip.Wvv = Wt_vis_v;
    ip.amr_qk = amr_qk_b; ip.vis_qk = vis_qk_b;
    ip.VTa = VT_amr; ip.VTv = VT_vis;
    ip.mask = amr_pad_mask; ip.keepP = keepP;
    ip.sqs = SQS;
    gemm_in<<<dim3(289, 4), 256, 0, stream>>>(ip);

    // 2) both attention directions, 1-wave blocks, parity-interleaved
    attn_fused<<<4096, 64, 0, stream>>>(
        amr_qk_b, vis_qk_b, VT_vis, VT_amr, keepP, ctx1_b, Pl, PaccB);
    combine_split<<<256, 256, 0, stream>>>(Pl, PaccB, ctx0_b);

    // 3) both output projections
    OutPack op;
    op.A[0] = ctx0_b; op.Wt[0] = Wt_amr_out; op.bias[0] = b_amr_out;
    op.feats[0] = amr_feats;    op.O[0] = out0;
    op.A[1] = ctx1_b; op.Wt[1] = Wt_vis_out; op.bias[1] = b_vis_out;
    op.feats[1] = visual_feats; op.O[1] = out1;
    gemm_out<<<dim3(288, 4), 256, 0, stream>>>(op);
}

// Round 19
// 88.273 us; speedup vs baseline: 1.0057x; 1.0057x over previous
//
#include <hip/hip_runtime.h>

#define BB 4
#define NN 512
#define MM 4096
#define DD 256
#define HH 8
#define HDD 32

typedef __attribute__((ext_vector_type(8))) short bf16x8;
typedef __attribute__((ext_vector_type(4))) float f32x4;
typedef __attribute__((ext_vector_type(4))) unsigned int u32x4;

__device__ __forceinline__ unsigned short f2b(float f) {
    union { float f; unsigned u; } v; v.f = f;
    unsigned r = v.u + 0x7fffu + ((v.u >> 16) & 1u);
    return (unsigned short)(r >> 16);
}
__device__ __forceinline__ float b2f(unsigned short u) {
    union { unsigned u; float f; } v; v.u = ((unsigned)u) << 16;
    return v.f;
}
// packed f32x2 -> bf16x2 (RNE)
__device__ __forceinline__ unsigned cvt_pk_bf16(float lo, float hi) {
    unsigned r;
    asm("v_cvt_pk_bf16_f32 %0, %1, %2" : "=v"(r) : "v"(lo), "v"(hi));
    return r;
}

// ---------------------------------------------------------------------------
// Weight convert+transpose via LDS tile. Wt[c][k] = bf16(W[k][c]).
// ---------------------------------------------------------------------------
struct WPack { const float* s[6]; unsigned short* d[6]; };
__global__ __launch_bounds__(256) void convert_w(WPack p)
{
    __shared__ unsigned short T[64][72];
    const int mat = blockIdx.x >> 4;
    const int tile = blockIdx.x & 15;
    const int kt = (tile >> 2) * 64, ct = (tile & 3) * 64;
    const int t = threadIdx.x;
    const int kl = t >> 2, cseg = (t & 3) * 16;

    const float* src = &p.s[mat][(size_t)(kt + kl) * DD + ct + cseg];
    #pragma unroll
    for (int j4 = 0; j4 < 4; ++j4) {
        const float4 f = *(const float4*)(src + j4 * 4);
        T[cseg + j4 * 4 + 0][kl] = f2b(f.x);
        T[cseg + j4 * 4 + 1][kl] = f2b(f.y);
        T[cseg + j4 * 4 + 2][kl] = f2b(f.z);
        T[cseg + j4 * 4 + 3][kl] = f2b(f.w);
    }
    __syncthreads();
    unsigned short* dst = &p.d[mat][(size_t)(ct + kl) * DD + kt + cseg];
    *(bf16x8*)dst       = *(const bf16x8*)&T[kl][cseg];
    *(bf16x8*)(dst + 8) = *(const bf16x8*)&T[kl][cseg + 8];
}

// ---------------------------------------------------------------------------
// Fused input projections: one block stages the f32 A tile ONCE per K-step
// and computes BOTH the qk-projection (head-packed out, scaled) and the
// V-projection (permuted-VT out, optional row mask) for that row-panel.
// ---------------------------------------------------------------------------
struct InPack {
    const float* amr; const float* vis;
    const unsigned short *Wqa, *Wva, *Wqv, *Wvv;
    unsigned short *amr_qk, *vis_qk, *VTa, *VTv;
    const int* mask;
    unsigned short* keepP;   // bf16 keep flags, VT-permuted, [B][NN]
    float sqs;
};
__global__ __launch_bounds__(256) void gemm_in(InPack p)
{
    __shared__ unsigned short As[64][72];
    __shared__ unsigned short Wq[64][72];
    __shared__ unsigned short Wv[64][72];

    const int bx = blockIdx.x;
    if (bx == 288) {
        if (blockIdx.y == 0) {
            // build keepP: bf16(mask?0:1) stored in the VT-permuted m order
            #pragma unroll
            for (int k8 = 0; k8 < 8; ++k8) {
                const int idx = k8 * 256 + threadIdx.x;
                const int m = idx & (NN - 1);
                const int r = m & 31;
                const int pp = ((r & 15) >> 2) * 8 + (r >> 4) * 4 + (r & 3);
                p.keepP[(idx & ~(NN - 1)) | (m & ~31) | pp]
                    = p.mask[idx] ? (unsigned short)0 : (unsigned short)0x3F80;
            }
        }
        return;
    }

    const float* A; const unsigned short *Wqm, *Wvm;
    unsigned short *Cq, *VT; const int* rowmask; int SEQ, r0;
    if (bx < 32) {
        A = p.amr; Wqm = p.Wqa; Wvm = p.Wva; Cq = p.amr_qk; VT = p.VTa;
        rowmask = p.mask; SEQ = NN; r0 = bx * 64;
    } else {
        A = p.vis; Wqm = p.Wqv; Wvm = p.Wvv; Cq = p.vis_qk; VT = p.VTv;
        rowmask = nullptr; SEQ = MM; r0 = (bx - 32) * 64;
    }
    const int c0 = blockIdx.y * 64;

    const int tid = threadIdx.x;
    const int lane = tid & 63, w = tid >> 6;
    const int rq = (w >> 1) * 32, cq = (w & 1) * 32;
    const int srow = tid >> 2, skc = (tid & 3) * 16;
    const int g = lane >> 4, cl = lane & 15;

    f32x4 aq[2][2] = {};   // qk-projection acc
    f32x4 av[2][2] = {};   // v-projection acc

    for (int ks = 0; ks < DD; ks += 64) {
        __syncthreads();
        {
            const float* ga = &A[(size_t)(r0 + srow) * DD + ks + skc];
            const float4 f0 = *(const float4*)(ga);
            const float4 f1 = *(const float4*)(ga + 4);
            const float4 f2 = *(const float4*)(ga + 8);
            const float4 f3 = *(const float4*)(ga + 12);
            uint4 u0, u1;
            u0.x = cvt_pk_bf16(f0.x, f0.y); u0.y = cvt_pk_bf16(f0.z, f0.w);
            u0.z = cvt_pk_bf16(f1.x, f1.y); u0.w = cvt_pk_bf16(f1.z, f1.w);
            u1.x = cvt_pk_bf16(f2.x, f2.y); u1.y = cvt_pk_bf16(f2.z, f2.w);
            u1.z = cvt_pk_bf16(f3.x, f3.y); u1.w = cvt_pk_bf16(f3.z, f3.w);
            *(uint4*)&As[srow][skc]     = u0;
            *(uint4*)&As[srow][skc + 8] = u1;
            const unsigned short* gq = &Wqm[(size_t)(c0 + srow) * DD + ks + skc];
            *(bf16x8*)&Wq[srow][skc]     = *(const bf16x8*)gq;
            *(bf16x8*)&Wq[srow][skc + 8] = *(const bf16x8*)(gq + 8);
            const unsigned short* gv = &Wvm[(size_t)(c0 + srow) * DD + ks + skc];
            *(bf16x8*)&Wv[srow][skc]     = *(const bf16x8*)gv;
            *(bf16x8*)&Wv[srow][skc + 8] = *(const bf16x8*)(gv + 8);
        }
        __syncthreads();
        #pragma unroll
        for (int kh = 0; kh < 2; ++kh) {
            const int kk = kh * 32 + g * 8;
            const bf16x8 a0 = *(const bf16x8*)&As[rq + cl][kk];
            const bf16x8 a1 = *(const bf16x8*)&As[rq + 16 + cl][kk];
            const bf16x8 q0 = *(const bf16x8*)&Wq[cq + cl][kk];
            const bf16x8 q1 = *(const bf16x8*)&Wq[cq + 16 + cl][kk];
            const bf16x8 v0 = *(const bf16x8*)&Wv[cq + cl][kk];
            const bf16x8 v1 = *(const bf16x8*)&Wv[cq + 16 + cl][kk];
            aq[0][0] = __builtin_amdgcn_mfma_f32_16x16x32_bf16(a0, q0, aq[0][0], 0, 0, 0);
            aq[0][1] = __builtin_amdgcn_mfma_f32_16x16x32_bf16(a0, q1, aq[0][1], 0, 0, 0);
            aq[1][0] = __builtin_amdgcn_mfma_f32_16x16x32_bf16(a1, q0, aq[1][0], 0, 0, 0);
            aq[1][1] = __builtin_amdgcn_mfma_f32_16x16x32_bf16(a1, q1, aq[1][1], 0, 0, 0);
            av[0][0] = __builtin_amdgcn_mfma_f32_16x16x32_bf16(a0, v0, av[0][0], 0, 0, 0);
            av[0][1] = __builtin_amdgcn_mfma_f32_16x16x32_bf16(a0, v1, av[0][1], 0, 0, 0);
            av[1][0] = __builtin_amdgcn_mfma_f32_16x16x32_bf16(a1, v0, av[1][0], 0, 0, 0);
            av[1][1] = __builtin_amdgcn_mfma_f32_16x16x32_bf16(a1, v1, av[1][1], 0, 0, 0);
        }
    }

    const int b0 = r0 / SEQ, mbase = r0 % SEQ;

    // qk output: head-packed
    #pragma unroll
    for (int sr = 0; sr < 2; ++sr)
    #pragma unroll
    for (int sc = 0; sc < 2; ++sc) {
        const int col = c0 + cq + sc * 16 + cl;
        const int head = col >> 5, c32 = col & 31;
        #pragma unroll
        for (int reg = 0; reg < 4; ++reg) {
            const int m = mbase + rq + sr * 16 + g * 4 + reg;
            Cq[(((size_t)b0 * HH + head) * SEQ + m) * 32 + c32]
                = f2b(aq[sr][sc][reg] * p.sqs);
        }
    }

    // v output: mask rows (dir-B), retile to permuted-VT via LDS
    if (rowmask != nullptr) {
        #pragma unroll
        for (int sr = 0; sr < 2; ++sr)
            #pragma unroll
            for (int reg = 0; reg < 4; ++reg) {
                const int m = mbase + rq + sr * 16 + g * 4 + reg;
                const float k = rowmask[b0 * SEQ + m] ? 0.f : 1.f;
                av[sr][0][reg] *= k;
                av[sr][1][reg] *= k;
            }
    }
    __syncthreads();
    #pragma unroll
    for (int sr = 0; sr < 2; ++sr)
    #pragma unroll
    for (int sc = 0; sc < 2; ++sc) {
        const int col_local = cq + sc * 16 + cl;
        uint2 u;
        u.x = cvt_pk_bf16(av[sr][sc][0], av[sr][sc][1]);
        u.y = cvt_pk_bf16(av[sr][sc][2], av[sr][sc][3]);
        *(uint2*)&As[col_local][rq + g * 8 + sr * 4] = u;
    }
    __syncthreads();
    {
        const int col = tid >> 2, seg = tid & 3;
        unsigned short* dst = &VT[((size_t)b0 * DD + c0 + col) * SEQ + mbase + seg * 16];
        *(bf16x8*)dst       = *(const bf16x8*)&As[col][seg * 16];
        *(bf16x8*)(dst + 8) = *(const bf16x8*)&As[col][seg * 16 + 8];
    }
}

// ---------------------------------------------------------------------------
// Output projection tile (A bf16 ctx row-major): out = (ctx@W + bias)*feats.
// ---------------------------------------------------------------------------
__device__ __forceinline__ void gemm_tile_out(
    const unsigned short* __restrict__ A,
    const unsigned short* __restrict__ Wt,
    const float* __restrict__ bias,
    const float* __restrict__ feats,
    float* __restrict__ Cf,
    int r0, int c0,
    unsigned short (*As)[72], unsigned short (*Ws)[72])
{
    const int tid = threadIdx.x;
    const int lane = tid & 63, w = tid >> 6;
    const int rq = (w >> 1) * 32, cq = (w & 1) * 32;
    const int srow = tid >> 2, skc = (tid & 3) * 16;
    const int g = lane >> 4, cl = lane & 15;

    f32x4 acc[2][2] = {};

    for (int ks = 0; ks < DD; ks += 64) {
        __syncthreads();
        {
            const unsigned short* ga = &A[(size_t)(r0 + srow) * DD + ks + skc];
            *(bf16x8*)&As[srow][skc]     = *(const bf16x8*)ga;
            *(bf16x8*)&As[srow][skc + 8] = *(const bf16x8*)(ga + 8);
            const unsigned short* gw = &Wt[(size_t)(c0 + srow) * DD + ks + skc];
            *(bf16x8*)&Ws[srow][skc]     = *(const bf16x8*)gw;
            *(bf16x8*)&Ws[srow][skc + 8] = *(const bf16x8*)(gw + 8);
        }
        __syncthreads();
        #pragma unroll
        for (int kh = 0; kh < 2; ++kh) {
            const int kk = kh * 32 + g * 8;
            const bf16x8 a0 = *(const bf16x8*)&As[rq + cl][kk];
            const bf16x8 a1 = *(const bf16x8*)&As[rq + 16 + cl][kk];
            const bf16x8 b0 = *(const bf16x8*)&Ws[cq + cl][kk];
            const bf16x8 b1 = *(const bf16x8*)&Ws[cq + 16 + cl][kk];
            acc[0][0] = __builtin_amdgcn_mfma_f32_16x16x32_bf16(a0, b0, acc[0][0], 0, 0, 0);
            acc[0][1] = __builtin_amdgcn_mfma_f32_16x16x32_bf16(a0, b1, acc[0][1], 0, 0, 0);
            acc[1][0] = __builtin_amdgcn_mfma_f32_16x16x32_bf16(a1, b0, acc[1][0], 0, 0, 0);
            acc[1][1] = __builtin_amdgcn_mfma_f32_16x16x32_bf16(a1, b1, acc[1][1], 0, 0, 0);
        }
    }

    #pragma unroll
    for (int sr = 0; sr < 2; ++sr)
    #pragma unroll
    for (int sc = 0; sc < 2; ++sc) {
        const int col = c0 + cq + sc * 16 + cl;
        #pragma unroll
        for (int reg = 0; reg < 4; ++reg) {
            const int row = r0 + rq + sr * 16 + g * 4 + reg;
            const size_t idx = (size_t)row * DD + col;
            Cf[idx] = (acc[sr][sc][reg] + bias[col]) * feats[idx];
        }
    }
}

struct OutPack {
    const unsigned short* A[2];
    const unsigned short* Wt[2];
    const float* bias[2];
    const float* feats[2];
    float* O[2];
};
__global__ __launch_bounds__(256) void gemm_out(OutPack p)
{
    __shared__ unsigned short As[64][72];
    __shared__ unsigned short Ws[64][72];
    const int bx = blockIdx.x;
    const int which = (bx < 32) ? 0 : 1;
    const int rb = (bx < 32) ? bx : bx - 32;
    gemm_tile_out(p.A[which], p.Wt[which], p.bias[which], p.feats[which],
                  p.O[which], rb * 64, blockIdx.y * 64, As, Ws);
}

// ---------------------------------------------------------------------------
// Attention body v9 (round-14 measured-green): 4-wave blocks, 64 q/wave,
// zero-LDS P, permuted VT, head-packed Q/K, MFMA denominator, keepP mask.
// ---------------------------------------------------------------------------
template<int SEQK, int SPLIT, bool HAS_KEEP>
__device__ __forceinline__ void attn_body(
    int bid,
    const unsigned short* __restrict__ Qb,    // head-packed [b][h][seq][32]
    const unsigned short* __restrict__ Kb,    // head-packed
    const unsigned short* __restrict__ VTb,   // permuted VT
    const unsigned short* __restrict__ keepP, // bf16 keep flags (permuted) or null
    unsigned short* __restrict__ ctx,         // row-major [b][nq][256]
    float* __restrict__ Pl, unsigned short* __restrict__ PaccB,
    int NQ)
{
    constexpr int KCHUNK = SEQK / SPLIT;
    constexpr int NT = KCHUNK / 64;

    const int tid = threadIdx.x;
    const int lane = tid & 63, w = tid >> 6;
    const int g = lane >> 4, cl = lane & 15;

    const int nqt = NQ / 256;
    int bi = bid;
    const int sp = bi % SPLIT; bi /= SPLIT;
    const int qt = bi % nqt;   bi /= nqt;
    const int h  = bi % HH;
    const int b  = bi / HH;
    const int q0 = qt * 256 + w * 64;
    const int kv0 = sp * KCHUNK;

    bf16x8 aq[4];
    #pragma unroll
    for (int qg = 0; qg < 4; ++qg)
        aq[qg] = *(const bf16x8*)
            &Qb[(((size_t)b * HH + h) * NQ + q0 + qg * 16 + cl) * 32 + g * 8];

    const unsigned short* Kp0 = Kb + (((size_t)b * HH + h) * SEQK + kv0 + cl) * 32 + g * 8;
    const unsigned short* Vp0 = VTb + ((size_t)b * DD + h * HDD + cl) * SEQK + kv0 + g * 8;
    const unsigned short* Op0 = HAS_KEEP ? (keepP + (size_t)b * SEQK + kv0 + g * 8) : nullptr;

    union { u32x4 u; bf16x8 b; } onesc;
    onesc.u[0] = 0x3F803F80u; onesc.u[1] = 0x3F803F80u;
    onesc.u[2] = 0x3F803F80u; onesc.u[3] = 0x3F803F80u;

    f32x4 acc[4][2] = {};
    f32x4 acc_l[4] = {};

    bf16x8 Kc[4], Kn[4];
    #pragma unroll
    for (int kf = 0; kf < 4; ++kf)
        Kc[kf] = *(const bf16x8*)(Kp0 + (size_t)(kf * 16) * 32);

    for (int t = 0; t < NT; ++t) {
        if (t + 1 < NT) {
            const unsigned short* kp = Kp0 + (size_t)((t + 1) * 64) * 32;
            #pragma unroll
            for (int kf = 0; kf < 4; ++kf)
                Kn[kf] = *(const bf16x8*)(kp + (size_t)(kf * 16) * 32);
        }

        bf16x8 vv[2][2];
        #pragma unroll
        for (int mh = 0; mh < 2; ++mh)
            #pragma unroll
            for (int sub = 0; sub < 2; ++sub)
                vv[mh][sub] = *(const bf16x8*)
                    (Vp0 + (size_t)(sub * 16) * SEQK + t * 64 + mh * 32);

        bf16x8 ofrag[2];
        if (HAS_KEEP) {
            ofrag[0] = *(const bf16x8*)(Op0 + t * 64);
            ofrag[1] = *(const bf16x8*)(Op0 + t * 64 + 32);
        } else {
            ofrag[0] = onesc.b;
            ofrag[1] = onesc.b;
        }

        uint2 X[4][4];
        #pragma unroll
        for (int kh = 0; kh < 2; ++kh) {
            f32x4 s[4][2];
            #pragma unroll
            for (int k2 = 0; k2 < 2; ++k2) {
                const f32x4 z = {0.f, 0.f, 0.f, 0.f};
                const bf16x8 kfrag = Kc[kh * 2 + k2];
                #pragma unroll
                for (int qg = 0; qg < 4; ++qg)
                    s[qg][k2] = __builtin_amdgcn_mfma_f32_16x16x32_bf16(
                        kfrag, aq[qg], z, 0, 0, 0);
            }
            #pragma unroll
            for (int k2 = 0; k2 < 2; ++k2) {
                const int kf = kh * 2 + k2;
                #pragma unroll
                for (int qg = 0; qg < 4; ++qg) {
                    const float p0 = exp2f(s[qg][k2][0]);
                    const float p1 = exp2f(s[qg][k2][1]);
                    const float p2 = exp2f(s[qg][k2][2]);
                    const float p3 = exp2f(s[qg][k2][3]);
                    X[qg][kf].x = cvt_pk_bf16(p0, p1);
                    X[qg][kf].y = cvt_pk_bf16(p2, p3);
                }
            }
        }

        #pragma unroll
        for (int mh = 0; mh < 2; ++mh) {
            union { u32x4 u; bf16x8 b; } pa[4];
            #pragma unroll
            for (int qg = 0; qg < 4; ++qg) {
                pa[qg].u[0] = X[qg][mh * 2].x;
                pa[qg].u[1] = X[qg][mh * 2].y;
                pa[qg].u[2] = X[qg][mh * 2 + 1].x;
                pa[qg].u[3] = X[qg][mh * 2 + 1].y;
            }
            #pragma unroll
            for (int sub = 0; sub < 2; ++sub)
                #pragma unroll
                for (int qg = 0; qg < 4; ++qg)
                    acc[qg][sub] = __builtin_amdgcn_mfma_f32_16x16x32_bf16(
                        pa[qg].b, vv[mh][sub], acc[qg][sub], 0, 0, 0);
            #pragma unroll
            for (int qg = 0; qg < 4; ++qg)
                acc_l[qg] = __builtin_amdgcn_mfma_f32_16x16x32_bf16(
                    pa[qg].b, ofrag[mh], acc_l[qg], 0, 0, 0);
        }

        #pragma unroll
        for (int kf = 0; kf < 4; ++kf) Kc[kf] = Kn[kf];
    }

    if (SPLIT > 1) {
        const int pb = bid;
        #pragma unroll
        for (int qg = 0; qg < 4; ++qg) {
            #pragma unroll
            for (int sub = 0; sub < 2; ++sub)
                #pragma unroll
                for (int reg = 0; reg < 4; ++reg) {
                    const int wq = w * 64 + qg * 16 + g * 4 + reg;
                    PaccB[((size_t)pb * 256 + wq) * 32 + sub * 16 + cl]
                        = f2b(acc[qg][sub][reg]);
                }
            if (cl == 0) {
                #pragma unroll
                for (int reg = 0; reg < 4; ++reg)
                    Pl[(size_t)pb * 256 + w * 64 + qg * 16 + g * 4 + reg]
                        = acc_l[qg][reg];
            }
        }
    } else {
        // acc_l rows align with acc rows -> direct divide, no shuffles
        #pragma unroll
        for (int qg = 0; qg < 4; ++qg)
            #pragma unroll
            for (int sub = 0; sub < 2; ++sub)
                #pragma unroll
                for (int reg = 0; reg < 4; ++reg) {
                    const int q = q0 + qg * 16 + g * 4 + reg;
                    ctx[((size_t)b * NQ + q) * DD + h * HDD + sub * 16 + cl]
                        = f2b(acc[qg][sub][reg] / acc_l[qg][reg]);
                }
    }
}

// Fused, parity-interleaved: even = dir A (512, SPLIT=8), odd = dir B (512).
__global__ __launch_bounds__(256) void attn_fused(
    const unsigned short* __restrict__ amr_qk,
    const unsigned short* __restrict__ vis_qk,
    const unsigned short* __restrict__ VT_vis,
    const unsigned short* __restrict__ VT_amr,
    const unsigned short* __restrict__ keepP,
    unsigned short* __restrict__ ctx1,
    float* __restrict__ Pl, unsigned short* __restrict__ PaccB)
{
    if ((blockIdx.x & 1) == 0) {
        attn_body<MM, 8, false>(blockIdx.x >> 1, amr_qk, vis_qk, VT_vis, nullptr,
                                nullptr, Pl, PaccB, NN);
    } else {
        attn_body<NN, 1, true>(blockIdx.x >> 1, vis_qk, amr_qk, VT_amr, keepP,
                               ctx1, nullptr, nullptr, MM);
    }
}

// Combine 8 split partials (bf16 acc, f32 l): out = sum(acc)/sum(l)
__global__ __launch_bounds__(256) void combine_split(
    const float* __restrict__ Pl, const unsigned short* __restrict__ PaccB,
    unsigned short* __restrict__ ctx)
{
    const int q = threadIdx.x;
    const int bqt = blockIdx.x;
    const int qt = bqt & 1, h = (bqt >> 1) & 7, b = bqt >> 4;
    const int pb0 = bqt * 8;

    float denom = 0.f;
    float o[32] = {};
    #pragma unroll
    for (int sp = 0; sp < 8; ++sp) {
        const size_t base = ((size_t)(pb0 + sp) * 256 + q) * 32;
        #pragma unroll
        for (int c8 = 0; c8 < 4; ++c8) {
            const bf16x8 a = *(const bf16x8*)&PaccB[base + c8 * 8];
            #pragma unroll
            for (int j = 0; j < 8; ++j)
                o[c8 * 8 + j] += b2f((unsigned short)a[j]);
        }
        denom += Pl[(size_t)(pb0 + sp) * 256 + q];
    }
    const float inv = 1.f / denom;

    unsigned short* dst = &ctx[((size_t)b * NN + qt * 256 + q) * DD + h * HDD];
    #pragma unroll
    for (int j4 = 0; j4 < 8; ++j4) {
        ushort4 u;
        u.x = f2b(o[j4 * 4 + 0] * inv); u.y = f2b(o[j4 * 4 + 1] * inv);
        u.z = f2b(o[j4 * 4 + 2] * inv); u.w = f2b(o[j4 * 4 + 3] * inv);
        *(ushort4*)(dst + j4 * 4) = u;
    }
}

// ---------------------------------------------------------------------------
extern "C" void kernel_launch(void* const* d_in, const int* in_sizes, int n_in,
                              void* d_out, int out_size, void* d_ws, size_t ws_size,
                              hipStream_t stream)
{
    const float* amr_feats    = (const float*)d_in[0];
    const int*   amr_pad_mask = (const int*)d_in[1];
    const float* visual_feats = (const float*)d_in[2];
    const float* W_amr_qk     = (const float*)d_in[3];
    const float* W_amr_v      = (const float*)d_in[4];
    const float* W_vis_qk     = (const float*)d_in[5];
    const float* W_vis_v      = (const float*)d_in[6];
    const float* W_amr_out    = (const float*)d_in[7];
    const float* b_amr_out    = (const float*)d_in[8];
    const float* W_vis_out    = (const float*)d_in[9];
    const float* b_vis_out    = (const float*)d_in[10];

    // workspace layout (u16 offsets), total ~38.6 MB
    unsigned short* ws = (unsigned short*)d_ws;
    unsigned short* Wt_amr_qk  = ws;                    // 6 x 65536
    unsigned short* Wt_amr_v   = ws + 65536;
    unsigned short* Wt_vis_qk  = ws + 131072;
    unsigned short* Wt_vis_v   = ws + 196608;
    unsigned short* Wt_amr_out = ws + 262144;
    unsigned short* Wt_vis_out = ws + 327680;
    unsigned short* amr_qk_b   = ws + 393216;           // 524288 (head-packed)
    unsigned short* VT_amr     = ws + 917504;           // 524288 (perm, masked rows zeroed)
    unsigned short* vis_qk_b   = ws + 1441792;          // 4194304 (head-packed)
    unsigned short* VT_vis     = ws + 5636096;          // 4194304
    unsigned short* ctx0_b     = ws + 9830400;          // 524288
    unsigned short* ctx1_b     = ws + 10354688;         // 4194304
    float* Pl                  = (float*)(ws + 14548992);  // 512*256 f32
    unsigned short* PaccB      = ws + 15073280;         // 512*256*32 bf16
    unsigned short* keepP      = ws + 19267584;         // 2048 bf16 (permuted)

    float* out0 = (float*)d_out;
    float* out1 = out0 + (size_t)BB * NN * DD;

    // sqrt( HD^-0.5 * log2(e) ) folded into BOTH qk projections -> exp2 domain
    const float SQS = 0.50500976f;

    // 0) weight convert+transpose
    WPack wp;
    wp.s[0] = W_amr_qk;  wp.d[0] = Wt_amr_qk;
    wp.s[1] = W_amr_v;   wp.d[1] = Wt_amr_v;
    wp.s[2] = W_vis_qk;  wp.d[2] = Wt_vis_qk;
    wp.s[3] = W_vis_v;   wp.d[3] = Wt_vis_v;
    wp.s[4] = W_amr_out; wp.d[4] = Wt_amr_out;
    wp.s[5] = W_vis_out; wp.d[5] = Wt_vis_out;
    convert_w<<<96, 256, 0, stream>>>(wp);

    // 1) fused input projections (+ keepP builder block)
    InPack ip;
    ip.amr = amr_feats; ip.vis = visual_feats;
    ip.Wqa = Wt_amr_qk; ip.Wva = Wt_amr_v;
    ip.Wqv = Wt_vis_qk; ip.Wvv = Wt_vis_v;
    ip.amr_qk = amr_qk_b; ip.vis_qk = vis_qk_b;
    ip.VTa = VT_amr; ip.VTv = VT_vis;
    ip.mask = amr_pad_mask; ip.keepP = keepP;
    ip.sqs = SQS;
    gemm_in<<<dim3(289, 4), 256, 0, stream>>>(ip);

    // 2) both attention directions, 4-wave blocks, parity-interleaved
    attn_fused<<<1024, 256, 0, stream>>>(
        amr_qk_b, vis_qk_b, VT_vis, VT_amr, keepP, ctx1_b, Pl, PaccB);
    combine_split<<<64, 256, 0, stream>>>(Pl, PaccB, ctx0_b);

    // 3) both output projections
    OutPack op;
    op.A[0] = ctx0_b; op.Wt[0] = Wt_amr_out; op.bias[0] = b_amr_out;
    op.feats[0] = amr_feats;    op.O[0] = out0;
    op.A[1] = ctx1_b; op.Wt[1] = Wt_vis_out; op.bias[1] = b_vis_out;
    op.feats[1] = visual_feats; op.O[1] = out1;
    gemm_out<<<dim3(288, 4), 256, 0, stream>>>(op);
}